// Round 2
// baseline (1580.164 us; speedup 1.0000x reference)
//
#include <hip/hip_runtime.h>
#include <stdint.h>

#define SEQ   2048
#define BATCH 2
#define HD    4096
#define NH    32
#define NKV   2
#define HDIM  128
#define NT    (SEQ*BATCH)   // 4096 tokens
#define KVC   (NKV*HDIM)    // 256

typedef short  bf16x8 __attribute__((ext_vector_type(8)));
typedef short  sh4    __attribute__((ext_vector_type(4)));
typedef float  f32x4  __attribute__((ext_vector_type(4)));

__device__ __forceinline__ float bf2f(unsigned short u){
  union { unsigned int i; float f; } v; v.i = ((unsigned int)u) << 16; return v.f;
}
__device__ __forceinline__ unsigned short f2bf(float f){
  union { float f; unsigned int i; } v; v.f = f;
  unsigned int r = v.i + 0x7FFFu + ((v.i >> 16) & 1u);
  return (unsigned short)(r >> 16);
}

// async global->LDS, 16B per lane; LDS dest is wave-uniform base + lane*16
__device__ __forceinline__ void gload_lds16(const void* g, void* lds){
  __builtin_amdgcn_global_load_lds(
      (const __attribute__((address_space(1))) unsigned int*)(size_t)g,
      (__attribute__((address_space(3))) unsigned int*)(unsigned int)(size_t)lds,
      16, 0, 0);
}

// ---------------- cast fp32 -> bf16 (vectorized) ----------------
__global__ void k_cast(const float* __restrict__ in, unsigned short* __restrict__ out, int n4){
  int i = blockIdx.x * blockDim.x + threadIdx.x;
  if (i >= n4) return;
  float4 v = ((const float4*)in)[i];
  ushort4 o; o.x = f2bf(v.x); o.y = f2bf(v.y); o.z = f2bf(v.z); o.w = f2bf(v.w);
  ((ushort4*)out)[i] = o;
}

// ---------------- W (KxN fp32) -> W^T (NxK bf16), LDS tiled ----------------
__global__ void k_transpose(const float* __restrict__ W, unsigned short* __restrict__ WT,
                            int K, int N){
  __shared__ float t[32][33];
  int n0 = blockIdx.x * 32, k0 = blockIdx.y * 32;
  int tx = threadIdx.x, ty = threadIdx.y;
  t[ty][tx] = W[(size_t)(k0 + ty) * N + n0 + tx];
  __syncthreads();
  WT[(size_t)(n0 + ty) * K + k0 + tx] = f2bf(t[tx][ty]);
}

// ---------------- GEMM: C[MxN] = A[MxK] * BT[NxK]^T + bias  (m97 structure) ----------------
template<bool OUTF32>
__global__ __launch_bounds__(256) void k_gemm(
    const unsigned short* __restrict__ A,
    const unsigned short* __restrict__ BT,
    const float* __restrict__ bias,
    void* __restrict__ C, int M, int N, int K)
{
  __shared__ unsigned short As[128*32];
  __shared__ unsigned short Bs[128*32];
  const int tid  = threadIdx.x;
  const int lane = tid & 63;
  const int w    = tid >> 6;
  const int l4   = lane >> 4, l15 = lane & 15;
  const int wm   = (w >> 1) * 64, wn = (w & 1) * 64;
  const size_t bm = (size_t)blockIdx.y * 128, bn = (size_t)blockIdx.x * 128;

  f32x4 acc[4][4] = {};
  const int scol = (lane & 3) * 8;   // element offset within a 32-elem row

  for (int k0 = 0; k0 < K; k0 += 32) {
    #pragma unroll
    for (int j = 0; j < 2; ++j) {
      const int r = w*32 + j*16 + (lane >> 2);
      gload_lds16(A  + (bm + r) * (size_t)K + k0 + scol, As + (size_t)(w*32 + j*16) * 32);
      gload_lds16(BT + (bn + r) * (size_t)K + k0 + scol, Bs + (size_t)(w*32 + j*16) * 32);
    }
    __syncthreads();
    bf16x8 af[4], bfr[4];
    #pragma unroll
    for (int m = 0; m < 4; ++m)
      af[m] = *(const bf16x8*)(As + (wm + m*16 + l15)*32 + l4*8);
    #pragma unroll
    for (int n = 0; n < 4; ++n)
      bfr[n] = *(const bf16x8*)(Bs + (wn + n*16 + l15)*32 + l4*8);
    #pragma unroll
    for (int m = 0; m < 4; ++m)
      #pragma unroll
      for (int n = 0; n < 4; ++n)
        acc[m][n] = __builtin_amdgcn_mfma_f32_16x16x32_bf16(af[m], bfr[n], acc[m][n], 0, 0, 0);
    __syncthreads();
  }

  #pragma unroll
  for (int n = 0; n < 4; ++n) {
    const size_t col = bn + wn + n*16 + l15;
    const float bv = bias ? bias[col] : 0.0f;
    #pragma unroll
    for (int m = 0; m < 4; ++m) {
      const size_t row0 = bm + wm + m*16 + l4*4;
      #pragma unroll
      for (int r = 0; r < 4; ++r) {
        float v = acc[m][n][r] + bv;
        if (OUTF32) ((float*)C)[(row0 + r) * (size_t)N + col] = v;
        else ((unsigned short*)C)[(row0 + r) * (size_t)N + col] = f2bf(v);
      }
    }
  }
}

// ---------------- RoPE + layout: [tok][cols] -> [b][slab][s][d], optional scale ----------------
__global__ void k_rope(const unsigned short* __restrict__ In, const float* __restrict__ rope,
                       unsigned short* __restrict__ Out, int ncols, int nslab, int psh, float sc)
{
  int idx = blockIdx.x * 256 + threadIdx.x;
  int npair = ncols >> 1;
  if (idx >= NT * npair) return;
  int t = idx >> psh, pr = idx & (npair - 1);
  int colp = pr * 2, h = colp >> 7, d = colp & 127;
  int s = t >> 1, b = t & 1;
  float x0 = bf2f(In[(size_t)t * ncols + colp]);
  float x1 = bf2f(In[(size_t)t * ncols + colp + 1]);
  float o0 = x0, o1 = x1;
  if (d < 64) {
    int i2 = d >> 1;
    float cr = rope[((size_t)s * 32 + i2) * 2 + 0];
    float ci = rope[((size_t)s * 32 + i2) * 2 + 1];
    o0 = x0 * cr - x1 * ci;
    o1 = x1 * cr + x0 * ci;
  }
  size_t dst = ((size_t)(b * nslab + h) * SEQ + s) * HDIM + d;
  Out[dst]     = f2bf(o0 * sc);
  Out[dst + 1] = f2bf(o1 * sc);
}

// ---------------- V: [tok][256] -> V^T [b][kv][d][s] ----------------
__global__ void k_vt(const unsigned short* __restrict__ In, unsigned short* __restrict__ Out){
  int idx = blockIdx.x * 256 + threadIdx.x;
  if (idx >= NT * KVC) return;
  int t = idx >> 8, cp = idx & 255;
  int kv = cp >> 7, d = cp & 127;
  int s = t >> 1, b = t & 1;
  Out[((size_t)(b * NKV + kv) * HDIM + d) * SEQ + s] = In[idx];
}

// ---------------- causal flash attention ----------------
// 4 waves/block (QBLK=64, 16 q-rows per wave), KVBLK=64, swapped QK^T:
// S^T = mfma(K, Q) puts a full score-row (q = lane&15) per lane -> softmax is
// 16 local ops + 2 shfl_xor (g-axis). P transposed via per-wave LDS (no barriers).
__global__ __launch_bounds__(256) void k_attn(
    const unsigned short* __restrict__ Q,    // [b][h][s][d], pre-scaled by 1/sqrt(d)
    const unsigned short* __restrict__ Kk,   // [b][kv][s][d]
    const unsigned short* __restrict__ Vt,   // [b][kv][d][s]
    unsigned short* __restrict__ Ctx)        // [tok][4096]
{
  const int tid  = threadIdx.x;
  const int lane = tid & 63;
  const int w    = tid >> 6;
  const int g = lane >> 4, c = lane & 15;
  const int bh = blockIdx.y;
  const int b = bh >> 5, h = bh & 31;
  const int qb  = (int)(gridDim.x - 1 - blockIdx.x);   // big causal tiles first
  const int qw0 = qb * 64 + w * 16;

  const unsigned short* Qb = Q  + ((size_t)(b * NH  + h)        * SEQ + qw0) * HDIM;
  const unsigned short* Kb = Kk + ((size_t)(b * NKV + (h >> 4)) * SEQ) * HDIM;
  const unsigned short* Vb = Vt + ((size_t)(b * NKV + (h >> 4)) * HDIM) * SEQ;

  __shared__ unsigned short Pl[4][16 * 72];   // per-wave, stride 72 elems (144B)
  unsigned short* P = Pl[w];

  bf16x8 qf[4];
  #pragma unroll
  for (int kk = 0; kk < 4; ++kk)
    qf[kk] = *(const bf16x8*)(Qb + (size_t)c * HDIM + kk*32 + g*8);

  f32x4 of[8] = {};
  float mrun = -1e30f, lrun = 0.0f;
  const int qmax = qw0 + 15;

  for (int t0 = 0; t0 < qw0 + 16; t0 += 64) {
    // ---- S^T tiles: st[T][r] = score(q = qw0+c, t = t0+T*16+g*4+r) ----
    f32x4 st[4];
    #pragma unroll
    for (int T = 0; T < 4; ++T) {
      if (t0 + T*16 <= qmax) {
        f32x4 s = {};
        #pragma unroll
        for (int kk = 0; kk < 4; ++kk) {
          bf16x8 kf = *(const bf16x8*)(Kb + (size_t)(t0 + T*16 + c) * HDIM + kk*32 + g*8);
          s = __builtin_amdgcn_mfma_f32_16x16x32_bf16(kf, qf[kk], s, 0, 0, 0);
        }
        #pragma unroll
        for (int r = 0; r < 4; ++r) {
          const int t = t0 + T*16 + g*4 + r;
          if (t > qw0 + c) s[r] = -1e30f;
        }
        st[T] = s;
      } else {
        st[T] = (f32x4){-1e30f, -1e30f, -1e30f, -1e30f};
      }
    }
    // ---- online softmax, all per-lane (q = c) ----
    float mloc = -1e30f;
    #pragma unroll
    for (int T = 0; T < 4; ++T)
      #pragma unroll
      for (int r = 0; r < 4; ++r)
        mloc = fmaxf(mloc, st[T][r]);
    mloc = fmaxf(mloc, __shfl_xor(mloc, 16));
    mloc = fmaxf(mloc, __shfl_xor(mloc, 32));
    const float mn = fmaxf(mrun, mloc);
    const float al = __expf(mrun - mn);
    mrun = mn;
    float ps = 0.0f;
    #pragma unroll
    for (int T = 0; T < 4; ++T) {
      sh4 pk;
      #pragma unroll
      for (int r = 0; r < 4; ++r) {
        const float p = __expf(st[T][r] - mn);
        ps += p;
        pk[r] = (short)f2bf(p);
      }
      *(sh4*)(P + c*72 + T*16 + g*4) = pk;   // P[q=c][t-block-local]
    }
    ps += __shfl_xor(ps, 16);
    ps += __shfl_xor(ps, 32);
    lrun = lrun * al + ps;
    // rescale O (O rows are q = qw0 + g*4 + r -> fetch al from lane g*4+r)
    float alr[4];
    #pragma unroll
    for (int r = 0; r < 4; ++r) alr[r] = __shfl(al, g*4 + r);
    #pragma unroll
    for (int d8 = 0; d8 < 8; ++d8)
      #pragma unroll
      for (int r = 0; r < 4; ++r)
        of[d8][r] *= alr[r];

    asm volatile("s_waitcnt lgkmcnt(0)" ::: "memory");
    __builtin_amdgcn_sched_barrier(0);

    // ---- PV: A = P[q][t] (k = t contiguous), B = V^T rows (col = d) ----
    const bf16x8 pa0 = *(const bf16x8*)(P + c*72 + g*8);
    #pragma unroll
    for (int d8 = 0; d8 < 8; ++d8) {
      bf16x8 vf = *(const bf16x8*)(Vb + (size_t)(d8*16 + c) * SEQ + t0 + g*8);
      of[d8] = __builtin_amdgcn_mfma_f32_16x16x32_bf16(pa0, vf, of[d8], 0, 0, 0);
    }
    if (t0 + 32 <= qmax) {
      const bf16x8 pa1 = *(const bf16x8*)(P + c*72 + 32 + g*8);
      #pragma unroll
      for (int d8 = 0; d8 < 8; ++d8) {
        bf16x8 vf = *(const bf16x8*)(Vb + (size_t)(d8*16 + c) * SEQ + t0 + 32 + g*8);
        of[d8] = __builtin_amdgcn_mfma_f32_16x16x32_bf16(pa1, vf, of[d8], 0, 0, 0);
      }
    }
  }

  // ---- epilogue: O row q = qw0 + g*4 + r, col = h*128 + d8*16 + c ----
  float lr[4];
  #pragma unroll
  for (int r = 0; r < 4; ++r) lr[r] = __shfl(lrun, g*4 + r);
  #pragma unroll
  for (int d8 = 0; d8 < 8; ++d8) {
    #pragma unroll
    for (int r = 0; r < 4; ++r) {
      const int s = qw0 + g*4 + r;
      const float v = of[d8][r] / lr[r];
      Ctx[((size_t)(s * BATCH + b)) * HD + (size_t)h * HDIM + d8*16 + c] = f2bf(v);
    }
  }
}

extern "C" void kernel_launch(void* const* d_in, const int* in_sizes, int n_in,
                              void* d_out, int out_size, void* d_ws, size_t ws_size,
                              hipStream_t stream)
{
  const float* hs   = (const float*)d_in[0];
  const float* rope = (const float*)d_in[1];
  const float* Wq   = (const float*)d_in[2];
  const float* bq   = (const float*)d_in[3];
  const float* Wk   = (const float*)d_in[4];
  const float* bk   = (const float*)d_in[5];
  const float* Wv   = (const float*)d_in[6];
  const float* bv   = (const float*)d_in[7];
  const float* Wo   = (const float*)d_in[8];

  char* ws = (char*)d_ws;
  const size_t MB = (size_t)1 << 20;
  unsigned short* Xbf  = (unsigned short*)(ws);             // 32MB
  unsigned short* Ctx  = Xbf;                               // alias: X dead after V-GEMM
  unsigned short* WqT  = (unsigned short*)(ws + 32*MB);     // 32MB
  unsigned short* Qa   = WqT;                               // alias: WqT dead after Q-GEMM
  unsigned short* WkT  = (unsigned short*)(ws + 64*MB);     // 2MB
  unsigned short* WvT  = (unsigned short*)(ws + 66*MB);     // 2MB
  unsigned short* WoT  = (unsigned short*)(ws + 68*MB);     // 32MB
  unsigned short* Qtmp = (unsigned short*)(ws + 100*MB);    // 32MB
  unsigned short* Ktmp = (unsigned short*)(ws + 132*MB);    // 2MB
  unsigned short* Vtmp = (unsigned short*)(ws + 134*MB);    // 2MB
  unsigned short* Ka   = (unsigned short*)(ws + 136*MB);    // 2MB
  unsigned short* VTa  = (unsigned short*)(ws + 138*MB);    // 2MB -> total 140MB

  k_cast<<<(NT*HD/4 + 255)/256, 256, 0, stream>>>(hs, Xbf, NT*HD/4);

  dim3 tb(32, 32);
  k_transpose<<<dim3(HD/32,  HD/32), tb, 0, stream>>>(Wq, WqT, HD, HD);
  k_transpose<<<dim3(KVC/32, HD/32), tb, 0, stream>>>(Wk, WkT, HD, KVC);
  k_transpose<<<dim3(KVC/32, HD/32), tb, 0, stream>>>(Wv, WvT, HD, KVC);
  k_transpose<<<dim3(HD/32,  HD/32), tb, 0, stream>>>(Wo, WoT, HD, HD);

  k_gemm<false><<<dim3(HD/128,  NT/128), 256, 0, stream>>>(Xbf, WqT, bq, Qtmp, NT, HD,  HD);
  k_gemm<false><<<dim3(KVC/128, NT/128), 256, 0, stream>>>(Xbf, WkT, bk, Ktmp, NT, KVC, HD);
  k_gemm<false><<<dim3(KVC/128, NT/128), 256, 0, stream>>>(Xbf, WvT, bv, Vtmp, NT, KVC, HD);

  const float sc = 0.08838834764831845f;  // 1/sqrt(128)
  k_rope<<<(NT*(HD/2)  + 255)/256, 256, 0, stream>>>(Qtmp, rope, Qa, HD,  NH,  11, sc);
  k_rope<<<(NT*(KVC/2) + 255)/256, 256, 0, stream>>>(Ktmp, rope, Ka, KVC, NKV, 7, 1.0f);
  k_vt  <<<(NT*KVC     + 255)/256, 256, 0, stream>>>(Vtmp, VTa);

  k_attn<<<dim3(SEQ/64, NH*BATCH), 256, 0, stream>>>(Qa, Ka, VTa, Ctx);

  k_gemm<true><<<dim3(HD/128, NT/128), 256, 0, stream>>>(Ctx, WoT, nullptr, d_out, NT, HD, HD);
}

// Round 3
// 940.950 us; speedup vs baseline: 1.6793x; 1.6793x over previous
//
#include <hip/hip_runtime.h>
#include <stdint.h>

#define SEQ   2048
#define BATCH 2
#define HD    4096
#define NH    32
#define NKV   2
#define HDIM  128
#define NT    (SEQ*BATCH)   // 4096 tokens
#define KVC   (NKV*HDIM)    // 256

typedef short  bf16x8 __attribute__((ext_vector_type(8)));
typedef short  sh4    __attribute__((ext_vector_type(4)));
typedef float  f32x4  __attribute__((ext_vector_type(4)));

__device__ __forceinline__ float bf2f(unsigned short u){
  union { unsigned int i; float f; } v; v.i = ((unsigned int)u) << 16; return v.f;
}
__device__ __forceinline__ unsigned short f2bf(float f){
  union { float f; unsigned int i; } v; v.f = f;
  unsigned int r = v.i + 0x7FFFu + ((v.i >> 16) & 1u);
  return (unsigned short)(r >> 16);
}

// async global->LDS, 16B per lane; LDS dest is wave-uniform base + lane*16
__device__ __forceinline__ void gload_lds16(const void* g, void* lds){
  __builtin_amdgcn_global_load_lds(
      (const __attribute__((address_space(1))) unsigned int*)(size_t)g,
      (__attribute__((address_space(3))) unsigned int*)(unsigned int)(size_t)lds,
      16, 0, 0);
}

// ---------------- cast fp32 -> bf16 (vectorized) ----------------
__global__ void k_cast(const float* __restrict__ in, unsigned short* __restrict__ out, int n4){
  int i = blockIdx.x * blockDim.x + threadIdx.x;
  if (i >= n4) return;
  float4 v = ((const float4*)in)[i];
  ushort4 o; o.x = f2bf(v.x); o.y = f2bf(v.y); o.z = f2bf(v.z); o.w = f2bf(v.w);
  ((ushort4*)out)[i] = o;
}

// ---------------- W (KxN fp32) -> W^T (NxK bf16), LDS tiled ----------------
__global__ void k_transpose(const float* __restrict__ W, unsigned short* __restrict__ WT,
                            int K, int N){
  __shared__ float t[32][33];
  int n0 = blockIdx.x * 32, k0 = blockIdx.y * 32;
  int tx = threadIdx.x, ty = threadIdx.y;
  t[ty][tx] = W[(size_t)(k0 + ty) * N + n0 + tx];
  __syncthreads();
  WT[(size_t)(n0 + ty) * K + k0 + tx] = f2bf(t[tx][ty]);
}

// ---------------- GEMM: C[MxN] = A[MxK] * BT[NxK]^T + bias  (m97 structure) ----------------
template<bool OUTF32>
__global__ __launch_bounds__(256) void k_gemm(
    const unsigned short* __restrict__ A,
    const unsigned short* __restrict__ BT,
    const float* __restrict__ bias,
    void* __restrict__ C, int M, int N, int K)
{
  __shared__ unsigned short As[128*32];
  __shared__ unsigned short Bs[128*32];
  const int tid  = threadIdx.x;
  const int lane = tid & 63;
  const int w    = tid >> 6;
  const int l4   = lane >> 4, l15 = lane & 15;
  const int wm   = (w >> 1) * 64, wn = (w & 1) * 64;
  const size_t bm = (size_t)blockIdx.y * 128, bn = (size_t)blockIdx.x * 128;

  f32x4 acc[4][4] = {};
  const int scol = (lane & 3) * 8;   // element offset within a 32-elem row

  for (int k0 = 0; k0 < K; k0 += 32) {
    #pragma unroll
    for (int j = 0; j < 2; ++j) {
      const int r = w*32 + j*16 + (lane >> 2);
      gload_lds16(A  + (bm + r) * (size_t)K + k0 + scol, As + (size_t)(w*32 + j*16) * 32);
      gload_lds16(BT + (bn + r) * (size_t)K + k0 + scol, Bs + (size_t)(w*32 + j*16) * 32);
    }
    __syncthreads();
    bf16x8 af[4], bfr[4];
    #pragma unroll
    for (int m = 0; m < 4; ++m)
      af[m] = *(const bf16x8*)(As + (wm + m*16 + l15)*32 + l4*8);
    #pragma unroll
    for (int n = 0; n < 4; ++n)
      bfr[n] = *(const bf16x8*)(Bs + (wn + n*16 + l15)*32 + l4*8);
    #pragma unroll
    for (int m = 0; m < 4; ++m)
      #pragma unroll
      for (int n = 0; n < 4; ++n)
        acc[m][n] = __builtin_amdgcn_mfma_f32_16x16x32_bf16(af[m], bfr[n], acc[m][n], 0, 0, 0);
    __syncthreads();
  }

  #pragma unroll
  for (int n = 0; n < 4; ++n) {
    const size_t col = bn + wn + n*16 + l15;
    const float bv = bias ? bias[col] : 0.0f;
    #pragma unroll
    for (int m = 0; m < 4; ++m) {
      const size_t row0 = bm + wm + m*16 + l4*4;
      #pragma unroll
      for (int r = 0; r < 4; ++r) {
        float v = acc[m][n][r] + bv;
        if (OUTF32) ((float*)C)[(row0 + r) * (size_t)N + col] = v;
        else ((unsigned short*)C)[(row0 + r) * (size_t)N + col] = f2bf(v);
      }
    }
  }
}

// ---------------- RoPE + layout: [tok][cols] -> [b][slab][s][d], optional scale ----------------
__global__ void k_rope(const unsigned short* __restrict__ In, const float* __restrict__ rope,
                       unsigned short* __restrict__ Out, int ncols, int nslab, int psh, float sc)
{
  int idx = blockIdx.x * 256 + threadIdx.x;
  int npair = ncols >> 1;
  if (idx >= NT * npair) return;
  int t = idx >> psh, pr = idx & (npair - 1);
  int colp = pr * 2, h = colp >> 7, d = colp & 127;
  int s = t >> 1, b = t & 1;
  float x0 = bf2f(In[(size_t)t * ncols + colp]);
  float x1 = bf2f(In[(size_t)t * ncols + colp + 1]);
  float o0 = x0, o1 = x1;
  if (d < 64) {
    int i2 = d >> 1;
    float cr = rope[((size_t)s * 32 + i2) * 2 + 0];
    float ci = rope[((size_t)s * 32 + i2) * 2 + 1];
    o0 = x0 * cr - x1 * ci;
    o1 = x1 * cr + x0 * ci;
  }
  size_t dst = ((size_t)(b * nslab + h) * SEQ + s) * HDIM + d;
  Out[dst]     = f2bf(o0 * sc);
  Out[dst + 1] = f2bf(o1 * sc);
}

// ---------------- V: [tok][256] -> V^T [b][kv][d][s] ----------------
__global__ void k_vt(const unsigned short* __restrict__ In, unsigned short* __restrict__ Out){
  int idx = blockIdx.x * 256 + threadIdx.x;
  if (idx >= NT * KVC) return;
  int t = idx >> 8, cp = idx & 255;
  int kv = cp >> 7, d = cp & 127;
  int s = t >> 1, b = t & 1;
  Out[((size_t)(b * NKV + kv) * HDIM + d) * SEQ + s] = In[idx];
}

// ---------------- causal flash attention ----------------
// 4 waves/block (QBLK=64, 16 q-rows/wave), KVBLK=64.
// K tile [64][128] and V^T tile [128][64] staged in LDS via global_load_lds with
// XOR-swizzle (pre-swizzled global source, swizzled ds_read: col_byte ^= (row&7)<<4).
// Swapped QK^T (S^T = mfma(K,Q)) keeps softmax per-lane + 2 shfl_xor.
__global__ __launch_bounds__(256) void k_attn(
    const unsigned short* __restrict__ Q,    // [b][h][s][d], pre-scaled by 1/sqrt(d)
    const unsigned short* __restrict__ Kk,   // [b][kv][s][d]
    const unsigned short* __restrict__ Vt,   // [b][kv][d][s]
    unsigned short* __restrict__ Ctx)        // [tok][4096]
{
  const int tid  = threadIdx.x;
  const int lane = tid & 63;
  const int w    = tid >> 6;
  const int g = lane >> 4, c = lane & 15;
  const int bh = blockIdx.y;
  const int b = bh >> 5, h = bh & 31;
  const int qb  = (int)(gridDim.x - 1 - blockIdx.x);   // big causal tiles first
  const int qw0 = qb * 64 + w * 16;

  const unsigned short* Qb = Q  + ((size_t)(b * NH  + h)        * SEQ + qw0) * HDIM;
  const char* Kb = (const char*)(Kk + ((size_t)(b * NKV + (h >> 4)) * SEQ) * HDIM);
  const char* Vb = (const char*)(Vt + ((size_t)(b * NKV + (h >> 4)) * HDIM) * SEQ);

  __shared__ unsigned short Ks[64*128];       // K tile, swizzled rows (256B)
  __shared__ unsigned short Vs[128*64];       // V^T tile, swizzled rows (128B)
  __shared__ unsigned short Pl[4][16 * 72];   // per-wave P, stride 72 elems
  unsigned short* P = Pl[w];

  bf16x8 qf[4];
  #pragma unroll
  for (int kk = 0; kk < 4; ++kk)
    qf[kk] = *(const bf16x8*)(Qb + (size_t)c * HDIM + kk*32 + g*8);

  f32x4 of[8] = {};
  float mrun = -1e30f, lrun = 0.0f;
  const int qmax = qw0 + 15;
  const int tblk = qb * 64 + 64;              // block causal extent

  // staging lane roles
  const int kr = lane >> 4, kc = lane & 15;   // K: 4 rows x 16 chunks per gload
  const int vr = lane >> 3, vc = lane & 7;    // V: 8 rows x 8 chunks per gload
  const int swz = (c & 7) << 4;               // read-side XOR (row&7 == c&7 for our rows)

  for (int t0 = 0; t0 < tblk; t0 += 64) {
    // ---- stage K[t0..t0+63][0..127] and VT[0..127][t0..t0+63] ----
    #pragma unroll
    for (int j = 0; j < 4; ++j) {
      const int r = w*16 + j*4 + kr;                       // K tile row
      gload_lds16(Kb + (size_t)(t0 + r) * 256 + ((kc*16) ^ ((r & 7) << 4)),
                  (char*)Ks + (w*16 + j*4) * 256);
    }
    #pragma unroll
    for (int j = 0; j < 4; ++j) {
      const int d = w*32 + j*8 + vr;                       // VT tile row (d)
      gload_lds16(Vb + (size_t)d * (SEQ*2) + (size_t)t0*2 + ((vc*16) ^ ((d & 7) << 4)),
                  (char*)Vs + (w*32 + j*8) * 128);
    }
    __syncthreads();

    // ---- S^T tiles: st[T][r] = score(q = qw0+c, t = t0+T*16+g*4+r) ----
    f32x4 st[4];
    #pragma unroll
    for (int T = 0; T < 4; ++T) {
      if (t0 + T*16 <= qmax) {
        f32x4 s = {};
        #pragma unroll
        for (int kk = 0; kk < 4; ++kk) {
          bf16x8 kf = *(const bf16x8*)((const char*)Ks + (T*16 + c)*256 + ((kk*64 + g*16) ^ swz));
          s = __builtin_amdgcn_mfma_f32_16x16x32_bf16(kf, qf[kk], s, 0, 0, 0);
        }
        #pragma unroll
        for (int r = 0; r < 4; ++r) {
          const int t = t0 + T*16 + g*4 + r;
          if (t > qw0 + c) s[r] = -1e30f;
        }
        st[T] = s;
      } else {
        st[T] = (f32x4){-1e30f, -1e30f, -1e30f, -1e30f};
      }
    }
    // ---- online softmax, per-lane (q = qw0+c) ----
    float mloc = -1e30f;
    #pragma unroll
    for (int T = 0; T < 4; ++T)
      #pragma unroll
      for (int r = 0; r < 4; ++r)
        mloc = fmaxf(mloc, st[T][r]);
    mloc = fmaxf(mloc, __shfl_xor(mloc, 16));
    mloc = fmaxf(mloc, __shfl_xor(mloc, 32));
    const float mn = fmaxf(mrun, mloc);
    const float al = __expf(mrun - mn);
    mrun = mn;
    float ps = 0.0f;
    #pragma unroll
    for (int T = 0; T < 4; ++T) {
      sh4 pk;
      #pragma unroll
      for (int r = 0; r < 4; ++r) {
        const float p = __expf(st[T][r] - mn);
        ps += p;
        pk[r] = (short)f2bf(p);
      }
      *(sh4*)(P + c*72 + T*16 + g*4) = pk;   // P[q=c][t-block-local]
    }
    ps += __shfl_xor(ps, 16);
    ps += __shfl_xor(ps, 32);
    lrun = lrun * al + ps;
    // rescale O (O rows are q = qw0 + g*4 + r -> fetch al from lane g*4+r)
    float alr[4];
    #pragma unroll
    for (int r = 0; r < 4; ++r) alr[r] = __shfl(al, g*4 + r);
    #pragma unroll
    for (int d8 = 0; d8 < 8; ++d8)
      #pragma unroll
      for (int r = 0; r < 4; ++r)
        of[d8][r] *= alr[r];

    asm volatile("s_waitcnt lgkmcnt(0)" ::: "memory");
    __builtin_amdgcn_sched_barrier(0);

    // ---- PV: A = P[q][t] (k = t contiguous), B = V^T rows from LDS ----
    const bf16x8 pa0 = *(const bf16x8*)(P + c*72 + g*8);
    #pragma unroll
    for (int d8 = 0; d8 < 8; ++d8) {
      bf16x8 vf = *(const bf16x8*)((const char*)Vs + (d8*16 + c)*128 + ((g*16) ^ swz));
      of[d8] = __builtin_amdgcn_mfma_f32_16x16x32_bf16(pa0, vf, of[d8], 0, 0, 0);
    }
    if (t0 + 32 <= qmax) {
      const bf16x8 pa1 = *(const bf16x8*)(P + c*72 + 32 + g*8);
      #pragma unroll
      for (int d8 = 0; d8 < 8; ++d8) {
        bf16x8 vf = *(const bf16x8*)((const char*)Vs + (d8*16 + c)*128 + ((64 + g*16) ^ swz));
        of[d8] = __builtin_amdgcn_mfma_f32_16x16x32_bf16(pa1, vf, of[d8], 0, 0, 0);
      }
    }
    __syncthreads();
  }

  // ---- epilogue: O row q = qw0 + g*4 + r, col = h*128 + d8*16 + c ----
  float lr[4];
  #pragma unroll
  for (int r = 0; r < 4; ++r) lr[r] = __shfl(lrun, g*4 + r);
  #pragma unroll
  for (int d8 = 0; d8 < 8; ++d8) {
    #pragma unroll
    for (int r = 0; r < 4; ++r) {
      const int s = qw0 + g*4 + r;
      const float v = of[d8][r] / lr[r];
      Ctx[((size_t)(s * BATCH + b)) * HD + (size_t)h * HDIM + d8*16 + c] = f2bf(v);
    }
  }
}

extern "C" void kernel_launch(void* const* d_in, const int* in_sizes, int n_in,
                              void* d_out, int out_size, void* d_ws, size_t ws_size,
                              hipStream_t stream)
{
  const float* hs   = (const float*)d_in[0];
  const float* rope = (const float*)d_in[1];
  const float* Wq   = (const float*)d_in[2];
  const float* bq   = (const float*)d_in[3];
  const float* Wk   = (const float*)d_in[4];
  const float* bk   = (const float*)d_in[5];
  const float* Wv   = (const float*)d_in[6];
  const float* bv   = (const float*)d_in[7];
  const float* Wo   = (const float*)d_in[8];

  char* ws = (char*)d_ws;
  const size_t MB = (size_t)1 << 20;
  unsigned short* Xbf  = (unsigned short*)(ws);             // 32MB
  unsigned short* Ctx  = Xbf;                               // alias: X dead after V-GEMM
  unsigned short* WqT  = (unsigned short*)(ws + 32*MB);     // 32MB
  unsigned short* Qa   = WqT;                               // alias: WqT dead after Q-GEMM
  unsigned short* WkT  = (unsigned short*)(ws + 64*MB);     // 2MB
  unsigned short* WvT  = (unsigned short*)(ws + 66*MB);     // 2MB
  unsigned short* WoT  = (unsigned short*)(ws + 68*MB);     // 32MB
  unsigned short* Qtmp = (unsigned short*)(ws + 100*MB);    // 32MB
  unsigned short* Ktmp = (unsigned short*)(ws + 132*MB);    // 2MB
  unsigned short* Vtmp = (unsigned short*)(ws + 134*MB);    // 2MB
  unsigned short* Ka   = (unsigned short*)(ws + 136*MB);    // 2MB
  unsigned short* VTa  = (unsigned short*)(ws + 138*MB);    // 2MB -> total 140MB

  k_cast<<<(NT*HD/4 + 255)/256, 256, 0, stream>>>(hs, Xbf, NT*HD/4);

  dim3 tb(32, 32);
  k_transpose<<<dim3(HD/32,  HD/32), tb, 0, stream>>>(Wq, WqT, HD, HD);
  k_transpose<<<dim3(KVC/32, HD/32), tb, 0, stream>>>(Wk, WkT, HD, KVC);
  k_transpose<<<dim3(KVC/32, HD/32), tb, 0, stream>>>(Wv, WvT, HD, KVC);
  k_transpose<<<dim3(HD/32,  HD/32), tb, 0, stream>>>(Wo, WoT, HD, HD);

  k_gemm<false><<<dim3(HD/128,  NT/128), 256, 0, stream>>>(Xbf, WqT, bq, Qtmp, NT, HD,  HD);
  k_gemm<false><<<dim3(KVC/128, NT/128), 256, 0, stream>>>(Xbf, WkT, bk, Ktmp, NT, KVC, HD);
  k_gemm<false><<<dim3(KVC/128, NT/128), 256, 0, stream>>>(Xbf, WvT, bv, Vtmp, NT, KVC, HD);

  const float sc = 0.08838834764831845f;  // 1/sqrt(128)
  k_rope<<<(NT*(HD/2)  + 255)/256, 256, 0, stream>>>(Qtmp, rope, Qa, HD,  NH,  11, sc);
  k_rope<<<(NT*(KVC/2) + 255)/256, 256, 0, stream>>>(Ktmp, rope, Ka, KVC, NKV, 7, 1.0f);
  k_vt  <<<(NT*KVC     + 255)/256, 256, 0, stream>>>(Vtmp, VTa);

  k_attn<<<dim3(SEQ/64, NH*BATCH), 256, 0, stream>>>(Qa, Ka, VTa, Ctx);

  k_gemm<true><<<dim3(HD/128, NT/128), 256, 0, stream>>>(Ctx, WoT, nullptr, d_out, NT, HD, HD);
}